// Round 7
// baseline (5013.579 us; speedup 1.0000x reference)
//
#include <hip/hip_runtime.h>
#include <stdint.h>
#include <math.h>

typedef __attribute__((ext_vector_type(8))) short bf16x8;
typedef __attribute__((ext_vector_type(4))) float f32x4;
typedef __attribute__((ext_vector_type(4))) unsigned short us4;
typedef __attribute__((ext_vector_type(4))) unsigned int ui4;

// ---------------- workspace layout (bytes) ----------------
constexpr size_t OFF_FLAGS  = 0;                          // 256 * 4
constexpr size_t OFF_RING   = 4096;                       // [8 slot][2 dir][64 b][512 k] u64 (tag|hi|mid|lo) = 4194304
constexpr size_t OFF_MASK   = OFF_RING + 4194304;         // [512 t][64 b] f32 = 131072
constexpr size_t OFF_XE_H   = OFF_MASK + 131072;          // [512 t][64 b][256 k] bf16 = 16777216
constexpr size_t OFF_XE_L   = OFF_XE_H + 16777216;
constexpr size_t OFF_HSEQ   = OFF_XE_L + 16777216;        // [2 dir][64 b][512 t][512 k] f32 = 134217728
constexpr size_t OFF_HLAST  = OFF_HSEQ + 134217728;       // [2 dir][64 b][512 k] f32 = 262144
constexpr size_t OFF_EMIS   = OFF_HLAST + 262144;         // [64 b][512 t][12] f32 = 1572864
// total ~174 MB

__device__ __forceinline__ unsigned short f2bf(float f) {
  unsigned u = __float_as_uint(f);
  unsigned r = 0x7fffu + ((u >> 16) & 1u);          // RNE
  return (unsigned short)((u + r) >> 16);
}
__device__ __forceinline__ float bf2f(unsigned short h) {
  return __uint_as_float(((unsigned)h) << 16);
}
__device__ __forceinline__ void split2(float v, unsigned short &a, unsigned short &b) {
  a = f2bf(v); b = f2bf(v - bf2f(a));
}
__device__ __forceinline__ void split3(float v, unsigned short &a, unsigned short &b, unsigned short &c) {
  a = f2bf(v); float r = v - bf2f(a);
  b = f2bf(r); float r2 = r - bf2f(b);
  c = f2bf(r2);
}
__device__ __forceinline__ float sigm(float x) {
  float e = expf(-fabsf(x));
  float s = 1.0f / (1.0f + e);
  return x >= 0.0f ? s : 1.0f - s;
}
__device__ __forceinline__ f32x4 mfma16(bf16x8 a, bf16x8 b, f32x4 c) {
  return __builtin_amdgcn_mfma_f32_16x16x32_bf16(a, b, c, 0, 0, 0);
}
// L3-coherence-point (agent-scope, fence-free) I/O
__device__ __forceinline__ unsigned long long ald64(const unsigned long long* p) {
  return __hip_atomic_load(p, __ATOMIC_RELAXED, __HIP_MEMORY_SCOPE_AGENT);
}
__device__ __forceinline__ void ast64(unsigned long long* p, unsigned long long v) {
  __hip_atomic_store(p, v, __ATOMIC_RELAXED, __HIP_MEMORY_SCOPE_AGENT);
}

// ---------------- prep: embeddings gather + hi/lo split, mask, zero-init ----------------
__global__ __launch_bounds__(256) void prep_k(const int* __restrict__ x,
                                              const float* __restrict__ emb,
                                              char* __restrict__ ws)
{
  const int bid = blockIdx.x, tid = threadIdx.x;
  if (bid < 8192) {                       // xe: 32768 rows x 64 segs (4 floats each)
    const int gi = bid * 256 + tid;
    const int row = gi >> 6;              // b*512 + t
    const int k = (gi & 63) * 4;
    const int b = row >> 9, t = row & 511;
    const int xid = x[row];
    const float4 v = *(const float4*)(emb + (size_t)xid * 256 + k);
    float vv[4] = {v.x, v.y, v.z, v.w};
    us4 H, L;
    #pragma unroll
    for (int j = 0; j < 4; ++j) {
      unsigned short hj, lj;
      split2(vv[j], hj, lj);
      H[j] = hj; L[j] = lj;
    }
    const size_t o = ((size_t)t * 64 + b) * 256 + k;
    *(us4*)((unsigned short*)(ws + OFF_XE_H) + o) = H;
    *(us4*)((unsigned short*)(ws + OFF_XE_L) + o) = L;
  } else if (bid < 8320) {                // mask
    const int gi = (bid - 8192) * 256 + tid;   // b*512 + t
    const int b = gi >> 9, t = gi & 511;
    ((float*)(ws + OFF_MASK))[t * 64 + b] = (x[gi] != 0) ? 1.0f : 0.0f;
  } else if (bid < 9344) {                // zero tagged ring (4 MB): tag 0 == valid zeros for step 0
    const int gi = (bid - 8320) * 256 + tid;
    ui4 z = {0u, 0u, 0u, 0u};
    ((ui4*)(ws + OFF_RING))[gi] = z;
  } else {                                // zero barrier flags
    ((int*)(ws + OFF_FLAGS))[tid] = 0;
  }
}

// ---------------- persistent bidirectional LSTM (3-way-split bf16 MFMA, ~fp32-exact) ----------------
// 256 WGs x 256 threads. WG = (dir, mg: 16 batch rows, ng: 16 h-cols -> 64 gate cols).
// h handoff: tag-carrying 8B atomic ring words [tag16|hi16|mid16|lo16], depth-8 slot ring.
// Consumers poll the data words directly in 2 batches of 16 (all loads in flight per retry).
// Producers: single tagged store, no drain, no flag on the critical path.
// Skew bound: flags published EVERY step (reads-done), checked every 4 steps (>= t-4,
// normally already satisfied). Slot reuse period 8 > max skew 7 => tags never skipped.
__global__ __launch_bounds__(256, 1) void lstm_k(
    const float* __restrict__ wih_f, const float* __restrict__ whh_f, const float* __restrict__ b_f,
    const float* __restrict__ wih_b, const float* __restrict__ whh_b, const float* __restrict__ b_b,
    char* __restrict__ ws)
{
  int* flags = (int*)(ws + OFF_FLAGS);
  unsigned long long* ringT = (unsigned long long*)(ws + OFF_RING);
  const float* maskf = (const float*)(ws + OFF_MASK);
  const unsigned short* xeH = (const unsigned short*)(ws + OFF_XE_H);
  const unsigned short* xeL = (const unsigned short*)(ws + OFF_XE_L);
  float* hseq  = (float*)(ws + OFF_HSEQ);
  float* hlast = (float*)(ws + OFF_HLAST);

  const int bid = blockIdx.x, tid = threadIdx.x;
  const int dir = bid & 1;
  const int mg  = (bid >> 1) & 3;          // batch group: rows [mg*16, mg*16+16)
  const int ng  = bid >> 3;                // 0..31: h-cols [ng*16, ng*16+16)
  int* gflags = flags + (dir * 4 + mg) * 32;   // skew-bound flags: 32 per group

  const float* whh  = dir ? whh_b : whh_f;
  const float* wih  = dir ? wih_b : wih_f;
  const float* bias = dir ? b_b  : b_f;

  const int kh = tid >> 6, lane = tid & 63;
  const int quad = lane >> 4, n16 = lane & 15;
  const int bRow = mg * 16 + n16;          // A-operand row (batch index)

  // B-operand (W^T) fragments in registers: gate g = ni (0..3 = i,f,g,o)
  bf16x8 bhh[4][4][3];   // [kt][ni][plane] 3-way split
  bf16x8 bhx[2][4][2];   // [xi][ni][plane] 2-way split
  #pragma unroll
  for (int ni = 0; ni < 4; ++ni) {
    const int grow = ni * 512 + ng * 16 + n16;   // weight row (gate column)
    const float* hrow = whh + (size_t)grow * 512;
    const float* xrow = wih + (size_t)grow * 256;
    #pragma unroll
    for (int kt = 0; kt < 4; ++kt) {
      const int k = (4 * kt + kh) * 32 + quad * 8;
      union { bf16x8 v; unsigned short s[8]; } H, M, L;
      #pragma unroll
      for (int j = 0; j < 8; ++j) split3(hrow[k + j], H.s[j], M.s[j], L.s[j]);
      bhh[kt][ni][0] = H.v; bhh[kt][ni][1] = M.v; bhh[kt][ni][2] = L.v;
    }
    #pragma unroll
    for (int xi = 0; xi < 2; ++xi) {
      const int k = (2 * kh + xi) * 32 + quad * 8;
      union { bf16x8 v; unsigned short s[8]; } H, L;
      #pragma unroll
      for (int j = 0; j < 8; ++j) split2(xrow[k + j], H.s[j], L.s[j]);
      bhx[xi][ni][0] = H.v; bhx[xi][ni][1] = L.v;
    }
  }

  // cell-update mapping: 256 threads = 16 rows x 16 h-cols (hcU fastest -> coalesced)
  const int rowU = tid >> 4, hcU = tid & 15;
  const int bU = mg * 16 + rowU;
  const int hcol = ng * 16 + hcU;
  const float bI = bias[hcol];
  const float bF = bias[512 + hcol];
  const float bG = bias[1024 + hcol];
  const float bO = bias[1536 + hcol];
  float cstate = 0.0f, hcarry = 0.0f;

  __shared__ float gbuf[2][4][16][65];   // [parity][kh][row][gatecol(+pad)]

  #pragma unroll 1
  for (int t = 0; t < 512; ++t) {
    const int tau = dir ? (511 - t) : t;
    const int par = t & 1;
    f32x4 aA[4], aB[4];
    const f32x4 z4 = {0.f, 0.f, 0.f, 0.f};
    #pragma unroll
    for (int ni = 0; ni < 4; ++ni) { aA[ni] = z4; aB[ni] = z4; }

    // ---- x-projection tiles: independent work, overlaps peers' ring stores ----
    #pragma unroll
    for (int xi = 0; xi < 2; ++xi) {
      const int kx = (2 * kh + xi) * 32 + quad * 8;
      const size_t o = ((size_t)tau * 64 + bRow) * 256 + kx;
      bf16x8 aH = *(const bf16x8*)(xeH + o);
      bf16x8 aL = *(const bf16x8*)(xeL + o);
      #pragma unroll
      for (int ni = 0; ni < 4; ++ni) {
        f32x4 a = (xi == 0) ? aA[ni] : aB[ni];
        a = mfma16(aH, bhx[xi][ni][0], a);
        a = mfma16(aH, bhx[xi][ni][1], a);
        a = mfma16(aL, bhx[xi][ni][0], a);
        a = mfma16(aL, bhx[xi][ni][1], a);
        if (xi == 0) aA[ni] = a; else aB[ni] = a;
      }
    }

    // ---- skew-bound check (every 4 steps; flags are per-step so this is normally free) ----
    if ((t & 3) == 0 && t != 0) {
      if (tid < 32) {
        while (__hip_atomic_load(&gflags[tid], __ATOMIC_RELAXED, __HIP_MEMORY_SCOPE_AGENT) < t - 4)
          __builtin_amdgcn_s_sleep(1);
      }
      // gates this step's ring writes via the __syncthreads below
    }

    // ---- recurrent tiles: poll tagged words in 2 batches of 16, MFMA per batch ----
    const size_t rb = (((size_t)(t & 7) * 2 + dir) * 64 + bRow) * 512;
    const unsigned texp = (unsigned)t & 0xffffu;
    #pragma unroll
    for (int half = 0; half < 2; ++half) {
      const int kt0 = 2 * half, kt1 = 2 * half + 1;
      const size_t o0 = rb + (4 * kt0 + kh) * 32 + quad * 8;
      const size_t o1 = rb + (4 * kt1 + kh) * 32 + quad * 8;
      unsigned long long w[16];
      for (;;) {
        #pragma unroll
        for (int j = 0; j < 8; ++j) {
          w[j]     = ald64(ringT + o0 + j);
          w[8 + j] = ald64(ringT + o1 + j);
        }
        unsigned bad = 0;
        #pragma unroll
        for (int j = 0; j < 16; ++j) bad |= ((unsigned)w[j] ^ texp) & 0xffffu;
        if (!__any((int)bad)) break;
      }
      #pragma unroll
      for (int sub = 0; sub < 2; ++sub) {
        const int kt = 2 * half + sub;
        union { bf16x8 v; unsigned short s[8]; } H, M, L;
        #pragma unroll
        for (int j = 0; j < 8; ++j) {
          const unsigned long long wj = w[sub * 8 + j];
          H.s[j] = (unsigned short)(wj >> 16);
          M.s[j] = (unsigned short)(wj >> 32);
          L.s[j] = (unsigned short)(wj >> 48);
        }
        #pragma unroll
        for (int ni = 0; ni < 4; ++ni) {
          f32x4 a = (kt & 1) ? aB[ni] : aA[ni];
          a = mfma16(H.v, bhh[kt][ni][0], a);
          a = mfma16(H.v, bhh[kt][ni][1], a);
          a = mfma16(M.v, bhh[kt][ni][0], a);
          a = mfma16(H.v, bhh[kt][ni][2], a);
          a = mfma16(M.v, bhh[kt][ni][1], a);
          a = mfma16(L.v, bhh[kt][ni][0], a);
          if (kt & 1) aB[ni] = a; else aA[ni] = a;
        }
      }
    }

    // ---- gates -> LDS (C/D layout: col = lane&15, row = quad*4 + reg) ----
    #pragma unroll
    for (int ni = 0; ni < 4; ++ni) {
      const f32x4 s = aA[ni] + aB[ni];
      #pragma unroll
      for (int r = 0; r < 4; ++r)
        gbuf[par][kh][quad * 4 + r][ni * 16 + n16] = s[r];
    }
    __syncthreads();   // the single per-step barrier (gbuf parity removes the second one)

    // publish "reads of step t complete" (off critical path; gates slot reuse only)
    if (tid == 0)
      __hip_atomic_store(&gflags[ng], t, __ATOMIC_RELAXED, __HIP_MEMORY_SCOPE_AGENT);

    // ---- LSTM cell update ----
    const float gi = gbuf[par][0][rowU][hcU]      + gbuf[par][1][rowU][hcU]      + gbuf[par][2][rowU][hcU]      + gbuf[par][3][rowU][hcU]      + bI;
    const float gf = gbuf[par][0][rowU][16 + hcU] + gbuf[par][1][rowU][16 + hcU] + gbuf[par][2][rowU][16 + hcU] + gbuf[par][3][rowU][16 + hcU] + bF;
    const float gg = gbuf[par][0][rowU][32 + hcU] + gbuf[par][1][rowU][32 + hcU] + gbuf[par][2][rowU][32 + hcU] + gbuf[par][3][rowU][32 + hcU] + bG;
    const float go = gbuf[par][0][rowU][48 + hcU] + gbuf[par][1][rowU][48 + hcU] + gbuf[par][2][rowU][48 + hcU] + gbuf[par][3][rowU][48 + hcU] + bO;
    const float m = maskf[tau * 64 + bU];
    const float iv = sigm(gi), fv = sigm(gf), gv = tanhf(gg), ov = sigm(go);
    const float cn = fv * cstate + iv * gv;
    const float hn = ov * tanhf(cn);
    const bool mm = (m > 0.5f);
    cstate = mm ? cn : cstate;
    hcarry = mm ? hn : hcarry;

    hseq[(((size_t)dir * 64 + bU) * 512 + tau) * 512 + hcol] = mm ? hn : 0.0f;
    {
      unsigned short hb, mb, lb;
      split3(hcarry, hb, mb, lb);
      const unsigned long long wv = (unsigned long long)((t + 1) & 0xffff)
                                  | ((unsigned long long)hb << 16)
                                  | ((unsigned long long)mb << 32)
                                  | ((unsigned long long)lb << 48);
      ast64(ringT + (((size_t)((t + 1) & 7) * 2 + dir) * 64 + bU) * 512 + hcol, wv);
    }
  }

  hlast[((size_t)dir * 64 + bU) * 512 + hcol] = hcarry;
}

// ---------------- emissions: hiddens @ fc_w^T + fc_b (fp64 accumulate) ----------------
__global__ __launch_bounds__(256) void emis_k(const float* __restrict__ fc_w,
                                              const float* __restrict__ fc_b,
                                              char* __restrict__ ws)
{
  __shared__ __align__(16) float fw[12 * 1024];
  __shared__ float fb[12];
  const int tid = threadIdx.x;
  for (int i = tid; i < 12 * 1024; i += 256) fw[i] = fc_w[i];
  if (tid < 12) fb[tid] = fc_b[tid];
  __syncthreads();
  const int row = blockIdx.x * 256 + tid;   // b*512 + tau
  const int b = row >> 9, tau = row & 511;
  const float* hs = (const float*)(ws + OFF_HSEQ);
  double acc[12];
  #pragma unroll
  for (int n = 0; n < 12; ++n) acc[n] = (double)fb[n];
  #pragma unroll 1
  for (int d = 0; d < 2; ++d) {
    const float4* hp = (const float4*)(hs + (((size_t)d * 64 + b) * 512 + tau) * 512);
    const float* fwd = fw + d * 512;
    for (int k4 = 0; k4 < 128; ++k4) {
      const float4 hv = hp[k4];
      #pragma unroll
      for (int n = 0; n < 12; ++n) {
        const float4 wv = *(const float4*)(fwd + n * 1024 + k4 * 4);
        acc[n] += (double)hv.x * wv.x + (double)hv.y * wv.y
                + (double)hv.z * wv.z + (double)hv.w * wv.w;
      }
    }
  }
  float* em = (float*)(ws + OFF_EMIS);
  #pragma unroll
  for (int n = 0; n < 12; ++n) em[(size_t)row * 12 + n] = (float)acc[n];
}

// ---------------- Viterbi decode (one wave per batch element) ----------------
__global__ __launch_bounds__(64) void viterbi_k(const float* __restrict__ trans,
                                                char* __restrict__ ws,
                                                float* __restrict__ out)
{
  const int b = blockIdx.x, lane = threadIdx.x;
  const float* eb = (const float*)(ws + OFF_EMIS) + (size_t)b * 6144;
  const float* maskf = (const float*)(ws + OFF_MASK);
  __shared__ float se[6144];
  __shared__ float sm[512];
  __shared__ unsigned char bp[512][12];
  for (int i = lane; i < 6144; i += 64) se[i] = eb[i];
  for (int i = lane; i < 512; i += 64) sm[i] = maskf[i * 64 + b];
  __syncthreads();
  const bool act = lane < 12;
  float tr[12];                         // tr[i] = trans[i][lane]
  #pragma unroll
  for (int i = 0; i < 12; ++i) tr[i] = act ? trans[i * 12 + lane] : 0.0f;
  float alpha = act ? (trans[120 + lane] + se[lane]) : -3.0e38f;   // BOS=10
  for (int t = 1; t < 512; ++t) {
    const float m = sm[t];
    float best = -3.0e38f; int bpi = 0;
    #pragma unroll
    for (int i = 0; i < 12; ++i) {
      const float s = __shfl(alpha, i) + tr[i];
      if (s > best) { best = s; bpi = i; }   // strict > keeps first max (jnp.argmax)
    }
    const float ev = act ? se[t * 12 + lane] : 0.0f;
    if (m > 0.5f) alpha = best + ev; else bpi = lane;
    if (act) bp[t][lane] = (unsigned char)bpi;
  }
  const float fin = act ? (alpha + trans[lane * 12 + 11]) : -3.0e38f;  // EOS=11
  float bestf = -3.0e38f; int bt = 0;
  #pragma unroll
  for (int j = 0; j < 12; ++j) {
    const float v = __shfl(fin, j);
    if (v > bestf) { bestf = v; bt = j; }
  }
  __syncthreads();
  if (lane == 0) {
    out[b] = bestf;
    int tag = bt;
    for (int t = 511; t >= 1; --t) {
      out[64 + (size_t)b * 512 + t] = (sm[t] > 0.5f) ? (float)tag : 0.0f;  // PAD=0
      tag = bp[t][tag];
    }
    out[64 + (size_t)b * 512] = (float)tag;   // t=0 always valid (len >= 256)
  }
}

// ---------------- classifier head: softmax(last_hidden @ fc2_w^T + fc2_b) ----------------
__global__ __launch_bounds__(64) void cls_k(const float* __restrict__ fc2_w,
                                            const float* __restrict__ fc2_b,
                                            char* __restrict__ ws,
                                            float* __restrict__ out)
{
  const int b = blockIdx.x, lane = threadIdx.x;
  const float* hl = (const float*)(ws + OFF_HLAST);
  float acc[10];
  #pragma unroll
  for (int c = 0; c < 10; ++c) acc[c] = 0.0f;
  #pragma unroll 1
  for (int kk = 0; kk < 16; ++kk) {
    const int k = lane * 16 + kk;
    const float hv = (k < 512) ? hl[(size_t)b * 512 + k]
                               : hl[((size_t)(64 + b)) * 512 + (k - 512)];
    #pragma unroll
    for (int c = 0; c < 10; ++c) acc[c] += hv * fc2_w[c * 1024 + k];
  }
  #pragma unroll
  for (int c = 0; c < 10; ++c) {
    #pragma unroll
    for (int off = 32; off >= 1; off >>= 1)
      acc[c] += __shfl_down(acc[c], off);
  }
  if (lane == 0) {
    float lg[10];
    float mx = -3.0e38f;
    #pragma unroll
    for (int c = 0; c < 10; ++c) { lg[c] = acc[c] + fc2_b[c]; mx = fmaxf(mx, lg[c]); }
    float s = 0.0f;
    #pragma unroll
    for (int c = 0; c < 10; ++c) { lg[c] = expf(lg[c] - mx); s += lg[c]; }
    const float inv = 1.0f / s;
    #pragma unroll
    for (int c = 0; c < 10; ++c) out[32832 + b * 10 + c] = lg[c] * inv;
  }
}

extern "C" void kernel_launch(void* const* d_in, const int* in_sizes, int n_in,
                              void* d_out, int out_size, void* d_ws, size_t ws_size,
                              hipStream_t stream)
{
  (void)in_sizes; (void)n_in; (void)out_size; (void)ws_size;
  const int*   x      = (const int*)d_in[0];
  const float* emb    = (const float*)d_in[1];
  const float* wih_f  = (const float*)d_in[2];
  const float* whh_f  = (const float*)d_in[3];
  const float* b_f    = (const float*)d_in[4];
  const float* wih_b  = (const float*)d_in[5];
  const float* whh_b  = (const float*)d_in[6];
  const float* b_b    = (const float*)d_in[7];
  const float* fc_w   = (const float*)d_in[8];
  const float* fc_b   = (const float*)d_in[9];
  const float* fc2_w  = (const float*)d_in[10];
  const float* fc2_b  = (const float*)d_in[11];
  const float* trans  = (const float*)d_in[12];
  char* ws = (char*)d_ws;
  float* out = (float*)d_out;

  prep_k<<<dim3(9345), dim3(256), 0, stream>>>(x, emb, ws);
  lstm_k<<<dim3(256), dim3(256), 0, stream>>>(wih_f, whh_f, b_f, wih_b, whh_b, b_b, ws);
  emis_k<<<dim3(128), dim3(256), 0, stream>>>(fc_w, fc_b, ws);
  cls_k<<<dim3(64), dim3(64), 0, stream>>>(fc2_w, fc2_b, ws, out);
  viterbi_k<<<dim3(64), dim3(64), 0, stream>>>(trans, ws, out);
}

// Round 8
// 2588.198 us; speedup vs baseline: 1.9371x; 1.9371x over previous
//
#include <hip/hip_runtime.h>
#include <stdint.h>
#include <math.h>

typedef __attribute__((ext_vector_type(8))) short bf16x8;
typedef __attribute__((ext_vector_type(4))) float f32x4;
typedef __attribute__((ext_vector_type(4))) unsigned short us4;
typedef __attribute__((ext_vector_type(4))) unsigned int ui4;

// ---------------- workspace layout (bytes) ----------------
constexpr size_t OFF_FLAGS  = 0;                          // 256 * 4 (pad to 4096)
constexpr size_t OFF_MASK   = 4096;                       // [512 t][64 b] f32 = 131072
constexpr size_t OFF_XE_H   = OFF_MASK + 131072;          // [512 t][64 b][256 k] bf16 = 16777216
constexpr size_t OFF_XE_L   = OFF_XE_H + 16777216;
constexpr size_t OFF_HSEQ   = OFF_XE_L + 16777216;        // [2 dir][64 b][512 t][512 k] f32 = 134217728
constexpr size_t OFF_HLAST  = OFF_HSEQ + 134217728;       // [2 dir][64 b][512 k] f32 = 262144
constexpr size_t OFF_EMIS   = OFF_HLAST + 262144;         // [64 b][512 t][12] f32 = 1572864
// total ~170 MB

__device__ __forceinline__ unsigned short f2bf(float f) {
  unsigned u = __float_as_uint(f);
  unsigned r = 0x7fffu + ((u >> 16) & 1u);          // RNE
  return (unsigned short)((u + r) >> 16);
}
__device__ __forceinline__ float bf2f(unsigned short h) {
  return __uint_as_float(((unsigned)h) << 16);
}
__device__ __forceinline__ void split2(float v, unsigned short &a, unsigned short &b) {
  a = f2bf(v); b = f2bf(v - bf2f(a));
}
__device__ __forceinline__ void split3(float v, unsigned short &a, unsigned short &b, unsigned short &c) {
  a = f2bf(v); float r = v - bf2f(a);
  b = f2bf(r); float r2 = r - bf2f(b);
  c = f2bf(r2);
}
__device__ __forceinline__ float sigm(float x) {
  float e = expf(-fabsf(x));
  float s = 1.0f / (1.0f + e);
  return x >= 0.0f ? s : 1.0f - s;
}
__device__ __forceinline__ f32x4 mfma16(bf16x8 a, bf16x8 b, f32x4 c) {
  return __builtin_amdgcn_mfma_f32_16x16x32_bf16(a, b, c, 0, 0, 0);
}
// agent-scope (L3 write-through) store: h must be visible to other XCDs' cached reads
__device__ __forceinline__ void ast32(unsigned int* p, unsigned v) {
  __hip_atomic_store(p, v, __ATOMIC_RELAXED, __HIP_MEMORY_SCOPE_AGENT);
}

// ---------------- prep: embeddings gather + hi/lo split, mask, zero flags ----------------
__global__ __launch_bounds__(256) void prep_k(const int* __restrict__ x,
                                              const float* __restrict__ emb,
                                              char* __restrict__ ws)
{
  const int bid = blockIdx.x, tid = threadIdx.x;
  if (bid < 8192) {                       // xe: 32768 rows x 64 segs (4 floats each)
    const int gi = bid * 256 + tid;
    const int row = gi >> 6;              // b*512 + t
    const int k = (gi & 63) * 4;
    const int b = row >> 9, t = row & 511;
    const int xid = x[row];
    const float4 v = *(const float4*)(emb + (size_t)xid * 256 + k);
    float vv[4] = {v.x, v.y, v.z, v.w};
    us4 H, L;
    #pragma unroll
    for (int j = 0; j < 4; ++j) {
      unsigned short hj, lj;
      split2(vv[j], hj, lj);
      H[j] = hj; L[j] = lj;
    }
    const size_t o = ((size_t)t * 64 + b) * 256 + k;
    *(us4*)((unsigned short*)(ws + OFF_XE_H) + o) = H;
    *(us4*)((unsigned short*)(ws + OFF_XE_L) + o) = L;
  } else if (bid < 8320) {                // mask
    const int gi = (bid - 8192) * 256 + tid;   // b*512 + t
    const int b = gi >> 9, t = gi & 511;
    ((float*)(ws + OFF_MASK))[t * 64 + b] = (x[gi] != 0) ? 1.0f : 0.0f;
  } else {                                // zero barrier flags
    ((int*)(ws + OFF_FLAGS))[tid] = 0;
  }
}

// ---------------- persistent bidirectional LSTM (3-way-split bf16 MFMA, ~fp32-exact) ----------------
// 256 WGs x 256 threads. WG = (dir, mg: 16 batch rows, ng: 16 h-cols -> 64 gate cols).
// h handoff: producers agent-store fp32 h into hseq (never-reused addresses); consumers,
// gated by a per-group 32-flag barrier, read it with PLAIN CACHED float4 loads (L2 serves
// the 32x replication; no stale-line hazard since every address is written exactly once
// and first touch is after the flag). 3-way bf16 split rebuilt in registers.
__global__ __launch_bounds__(256, 1) void lstm_k(
    const float* __restrict__ wih_f, const float* __restrict__ whh_f, const float* __restrict__ b_f,
    const float* __restrict__ wih_b, const float* __restrict__ whh_b, const float* __restrict__ b_b,
    char* __restrict__ ws)
{
  int* flags = (int*)(ws + OFF_FLAGS);
  const float* maskf = (const float*)(ws + OFF_MASK);
  const unsigned short* xeH = (const unsigned short*)(ws + OFF_XE_H);
  const unsigned short* xeL = (const unsigned short*)(ws + OFF_XE_L);
  float* hseq  = (float*)(ws + OFF_HSEQ);
  float* hlast = (float*)(ws + OFF_HLAST);

  const int bid = blockIdx.x, tid = threadIdx.x;
  const int dir = bid & 1;
  const int mg  = (bid >> 1) & 3;          // batch group: rows [mg*16, mg*16+16)
  const int ng  = bid >> 3;                // 0..31: h-cols [ng*16, ng*16+16)
  int* gflags = flags + (dir * 4 + mg) * 32;   // group barrier: 32 flags

  const float* whh  = dir ? whh_b : whh_f;
  const float* wih  = dir ? wih_b : wih_f;
  const float* bias = dir ? b_b  : b_f;

  const int kh = tid >> 6, lane = tid & 63;
  const int quad = lane >> 4, n16 = lane & 15;
  const int bRow = mg * 16 + n16;          // A-operand row (batch index)

  // B-operand (W^T) fragments in registers: gate g = ni (0..3 = i,f,g,o)
  bf16x8 bhh[4][4][3];   // [kt][ni][plane] 3-way split
  bf16x8 bhx[2][4][2];   // [xi][ni][plane] 2-way split
  #pragma unroll
  for (int ni = 0; ni < 4; ++ni) {
    const int grow = ni * 512 + ng * 16 + n16;   // weight row (gate column)
    const float* hrow = whh + (size_t)grow * 512;
    const float* xrow = wih + (size_t)grow * 256;
    #pragma unroll
    for (int kt = 0; kt < 4; ++kt) {
      const int k = (4 * kt + kh) * 32 + quad * 8;
      union { bf16x8 v; unsigned short s[8]; } H, M, L;
      #pragma unroll
      for (int j = 0; j < 8; ++j) split3(hrow[k + j], H.s[j], M.s[j], L.s[j]);
      bhh[kt][ni][0] = H.v; bhh[kt][ni][1] = M.v; bhh[kt][ni][2] = L.v;
    }
    #pragma unroll
    for (int xi = 0; xi < 2; ++xi) {
      const int k = (2 * kh + xi) * 32 + quad * 8;
      union { bf16x8 v; unsigned short s[8]; } H, L;
      #pragma unroll
      for (int j = 0; j < 8; ++j) split2(xrow[k + j], H.s[j], L.s[j]);
      bhx[xi][ni][0] = H.v; bhx[xi][ni][1] = L.v;
    }
  }

  // cell-update mapping: 256 threads = 16 rows x 16 h-cols (hcU fastest -> coalesced)
  const int rowU = tid >> 4, hcU = tid & 15;
  const int bU = mg * 16 + rowU;
  const int hcol = ng * 16 + hcU;
  const float bI = bias[hcol];
  const float bF = bias[512 + hcol];
  const float bG = bias[1024 + hcol];
  const float bO = bias[1536 + hcol];
  float cstate = 0.0f, hcarry = 0.0f;

  __shared__ float gbuf[4][16][65];   // [kh][row][gatecol(+pad)]

  #pragma unroll 1
  for (int t = 0; t < 512; ++t) {
    const int tau = dir ? (511 - t) : t;
    f32x4 acc[4];
    const f32x4 z4 = {0.f, 0.f, 0.f, 0.f};
    #pragma unroll
    for (int ni = 0; ni < 4; ++ni) acc[ni] = z4;

    // ---- x-projection tiles: independent work, overlaps the flag wait below ----
    #pragma unroll
    for (int xi = 0; xi < 2; ++xi) {
      const int kx = (2 * kh + xi) * 32 + quad * 8;
      const size_t o = ((size_t)tau * 64 + bRow) * 256 + kx;
      bf16x8 aH = *(const bf16x8*)(xeH + o);
      bf16x8 aL = *(const bf16x8*)(xeL + o);
      #pragma unroll
      for (int ni = 0; ni < 4; ++ni) {
        f32x4 a = acc[ni];
        a = mfma16(aH, bhx[xi][ni][0], a);
        a = mfma16(aH, bhx[xi][ni][1], a);
        a = mfma16(aL, bhx[xi][ni][0], a);
        a = mfma16(aL, bhx[xi][ni][1], a);
        acc[ni] = a;
      }
    }

    // ---- group flag wait: peers finished storing h for step t-1 ----
    if (t > 0) {
      if (tid < 32) {
        while (__hip_atomic_load(&gflags[tid], __ATOMIC_RELAXED, __HIP_MEMORY_SCOPE_AGENT) < t)
          __builtin_amdgcn_s_sleep(1);
      }
    }
    __syncthreads();   // sync#1: gates first touch of hseq[tauP]; compiler barrier vs spin

    // ---- recurrent tiles: cached float4 loads of hseq, register 3-way split, MFMA ----
    if (t > 0) {
      const int tauP = dir ? (tau + 1) : (tau - 1);
      const float* hb = hseq + (((size_t)dir * 64 + bRow) * 512 + tauP) * 512;
      float4 hv[8];
      #pragma unroll
      for (int kt = 0; kt < 4; ++kt) {
        const int k = (4 * kt + kh) * 32 + quad * 8;
        hv[2 * kt]     = *(const float4*)(hb + k);
        hv[2 * kt + 1] = *(const float4*)(hb + k + 4);
      }
      #pragma unroll
      for (int kt = 0; kt < 4; ++kt) {
        union { bf16x8 v; unsigned short s[8]; } H, M, L;
        float vv[8];
        *(float4*)&vv[0] = hv[2 * kt];
        *(float4*)&vv[4] = hv[2 * kt + 1];
        #pragma unroll
        for (int j = 0; j < 8; ++j) split3(vv[j], H.s[j], M.s[j], L.s[j]);
        #pragma unroll
        for (int ni = 0; ni < 4; ++ni) {
          f32x4 a = acc[ni];
          a = mfma16(H.v, bhh[kt][ni][0], a);
          a = mfma16(H.v, bhh[kt][ni][1], a);
          a = mfma16(M.v, bhh[kt][ni][0], a);
          a = mfma16(H.v, bhh[kt][ni][2], a);
          a = mfma16(M.v, bhh[kt][ni][1], a);
          a = mfma16(L.v, bhh[kt][ni][0], a);
          acc[ni] = a;
        }
      }
    }

    // ---- gates -> LDS (C/D layout: col = lane&15, row = quad*4 + reg) ----
    #pragma unroll
    for (int ni = 0; ni < 4; ++ni)
      #pragma unroll
      for (int r = 0; r < 4; ++r)
        gbuf[kh][quad * 4 + r][ni * 16 + n16] = acc[ni][r];
    __syncthreads();   // sync#2

    // ---- LSTM cell update ----
    const float gi = gbuf[0][rowU][hcU]      + gbuf[1][rowU][hcU]      + gbuf[2][rowU][hcU]      + gbuf[3][rowU][hcU]      + bI;
    const float gf = gbuf[0][rowU][16 + hcU] + gbuf[1][rowU][16 + hcU] + gbuf[2][rowU][16 + hcU] + gbuf[3][rowU][16 + hcU] + bF;
    const float gg = gbuf[0][rowU][32 + hcU] + gbuf[1][rowU][32 + hcU] + gbuf[2][rowU][32 + hcU] + gbuf[3][rowU][32 + hcU] + bG;
    const float go = gbuf[0][rowU][48 + hcU] + gbuf[1][rowU][48 + hcU] + gbuf[2][rowU][48 + hcU] + gbuf[3][rowU][48 + hcU] + bO;
    const float m = maskf[tau * 64 + bU];
    const float iv = sigm(gi), fv = sigm(gf), gv = tanhf(gg), ov = sigm(go);
    const float cn = fv * cstate + iv * gv;
    const float hn = ov * tanhf(cn);
    const bool mm = (m > 0.5f);
    cstate = mm ? cn : cstate;
    hcarry = mm ? hn : hcarry;

    // h for the recurrence AND emissions: agent store (write-through, L3-visible).
    // Masked rows store 0 -- harmless for the GEMM (their gate outputs are discarded).
    ast32((unsigned int*)(hseq + (((size_t)dir * 64 + bU) * 512 + tau) * 512 + hcol),
          __float_as_uint(mm ? hn : 0.0f));

    __syncthreads();   // sync#3: drains vmcnt -> this WG's h stores are in L3
    if (tid == 0)
      __hip_atomic_store(&gflags[ng], t + 1, __ATOMIC_RELAXED, __HIP_MEMORY_SCOPE_AGENT);
  }

  hlast[((size_t)dir * 64 + bU) * 512 + hcol] = hcarry;
}

// ---------------- emissions: hiddens @ fc_w^T + fc_b (fp64 accumulate) ----------------
__global__ __launch_bounds__(256) void emis_k(const float* __restrict__ fc_w,
                                              const float* __restrict__ fc_b,
                                              char* __restrict__ ws)
{
  __shared__ __align__(16) float fw[12 * 1024];
  __shared__ float fb[12];
  const int tid = threadIdx.x;
  for (int i = tid; i < 12 * 1024; i += 256) fw[i] = fc_w[i];
  if (tid < 12) fb[tid] = fc_b[tid];
  __syncthreads();
  const int row = blockIdx.x * 256 + tid;   // b*512 + tau
  const int b = row >> 9, tau = row & 511;
  const float* hs = (const float*)(ws + OFF_HSEQ);
  double acc[12];
  #pragma unroll
  for (int n = 0; n < 12; ++n) acc[n] = (double)fb[n];
  #pragma unroll 1
  for (int d = 0; d < 2; ++d) {
    const float4* hp = (const float4*)(hs + (((size_t)d * 64 + b) * 512 + tau) * 512);
    const float* fwd = fw + d * 512;
    for (int k4 = 0; k4 < 128; ++k4) {
      const float4 hv = hp[k4];
      #pragma unroll
      for (int n = 0; n < 12; ++n) {
        const float4 wv = *(const float4*)(fwd + n * 1024 + k4 * 4);
        acc[n] += (double)hv.x * wv.x + (double)hv.y * wv.y
                + (double)hv.z * wv.z + (double)hv.w * wv.w;
      }
    }
  }
  float* em = (float*)(ws + OFF_EMIS);
  #pragma unroll
  for (int n = 0; n < 12; ++n) em[(size_t)row * 12 + n] = (float)acc[n];
}

// ---------------- Viterbi decode (one wave per batch element) ----------------
__global__ __launch_bounds__(64) void viterbi_k(const float* __restrict__ trans,
                                                char* __restrict__ ws,
                                                float* __restrict__ out)
{
  const int b = blockIdx.x, lane = threadIdx.x;
  const float* eb = (const float*)(ws + OFF_EMIS) + (size_t)b * 6144;
  const float* maskf = (const float*)(ws + OFF_MASK);
  __shared__ float se[6144];
  __shared__ float sm[512];
  __shared__ unsigned char bp[512][12];
  for (int i = lane; i < 6144; i += 64) se[i] = eb[i];
  for (int i = lane; i < 512; i += 64) sm[i] = maskf[i * 64 + b];
  __syncthreads();
  const bool act = lane < 12;
  float tr[12];                         // tr[i] = trans[i][lane]
  #pragma unroll
  for (int i = 0; i < 12; ++i) tr[i] = act ? trans[i * 12 + lane] : 0.0f;
  float alpha = act ? (trans[120 + lane] + se[lane]) : -3.0e38f;   // BOS=10
  for (int t = 1; t < 512; ++t) {
    const float m = sm[t];
    float best = -3.0e38f; int bpi = 0;
    #pragma unroll
    for (int i = 0; i < 12; ++i) {
      const float s = __shfl(alpha, i) + tr[i];
      if (s > best) { best = s; bpi = i; }   // strict > keeps first max (jnp.argmax)
    }
    const float ev = act ? se[t * 12 + lane] : 0.0f;
    if (m > 0.5f) alpha = best + ev; else bpi = lane;
    if (act) bp[t][lane] = (unsigned char)bpi;
  }
  const float fin = act ? (alpha + trans[lane * 12 + 11]) : -3.0e38f;  // EOS=11
  float bestf = -3.0e38f; int bt = 0;
  #pragma unroll
  for (int j = 0; j < 12; ++j) {
    const float v = __shfl(fin, j);
    if (v > bestf) { bestf = v; bt = j; }
  }
  __syncthreads();
  if (lane == 0) {
    out[b] = bestf;
    int tag = bt;
    for (int t = 511; t >= 1; --t) {
      out[64 + (size_t)b * 512 + t] = (sm[t] > 0.5f) ? (float)tag : 0.0f;  // PAD=0
      tag = bp[t][tag];
    }
    out[64 + (size_t)b * 512] = (float)tag;   // t=0 always valid (len >= 256)
  }
}

// ---------------- classifier head: softmax(last_hidden @ fc2_w^T + fc2_b) ----------------
__global__ __launch_bounds__(64) void cls_k(const float* __restrict__ fc2_w,
                                            const float* __restrict__ fc2_b,
                                            char* __restrict__ ws,
                                            float* __restrict__ out)
{
  const int b = blockIdx.x, lane = threadIdx.x;
  const float* hl = (const float*)(ws + OFF_HLAST);
  float acc[10];
  #pragma unroll
  for (int c = 0; c < 10; ++c) acc[c] = 0.0f;
  #pragma unroll 1
  for (int kk = 0; kk < 16; ++kk) {
    const int k = lane * 16 + kk;
    const float hv = (k < 512) ? hl[(size_t)b * 512 + k]
                               : hl[((size_t)(64 + b)) * 512 + (k - 512)];
    #pragma unroll
    for (int c = 0; c < 10; ++c) acc[c] += hv * fc2_w[c * 1024 + k];
  }
  #pragma unroll
  for (int c = 0; c < 10; ++c) {
    #pragma unroll
    for (int off = 32; off >= 1; off >>= 1)
      acc[c] += __shfl_down(acc[c], off);
  }
  if (lane == 0) {
    float lg[10];
    float mx = -3.0e38f;
    #pragma unroll
    for (int c = 0; c < 10; ++c) { lg[c] = acc[c] + fc2_b[c]; mx = fmaxf(mx, lg[c]); }
    float s = 0.0f;
    #pragma unroll
    for (int c = 0; c < 10; ++c) { lg[c] = expf(lg[c] - mx); s += lg[c]; }
    const float inv = 1.0f / s;
    #pragma unroll
    for (int c = 0; c < 10; ++c) out[32832 + b * 10 + c] = lg[c] * inv;
  }
}

extern "C" void kernel_launch(void* const* d_in, const int* in_sizes, int n_in,
                              void* d_out, int out_size, void* d_ws, size_t ws_size,
                              hipStream_t stream)
{
  (void)in_sizes; (void)n_in; (void)out_size; (void)ws_size;
  const int*   x      = (const int*)d_in[0];
  const float* emb    = (const float*)d_in[1];
  const float* wih_f  = (const float*)d_in[2];
  const float* whh_f  = (const float*)d_in[3];
  const float* b_f    = (const float*)d_in[4];
  const float* wih_b  = (const float*)d_in[5];
  const float* whh_b  = (const float*)d_in[6];
  const float* b_b    = (const float*)d_in[7];
  const float* fc_w   = (const float*)d_in[8];
  const float* fc_b   = (const float*)d_in[9];
  const float* fc2_w  = (const float*)d_in[10];
  const float* fc2_b  = (const float*)d_in[11];
  const float* trans  = (const float*)d_in[12];
  char* ws = (char*)d_ws;
  float* out = (float*)d_out;

  prep_k<<<dim3(8321), dim3(256), 0, stream>>>(x, emb, ws);
  lstm_k<<<dim3(256), dim3(256), 0, stream>>>(wih_f, whh_f, b_f, wih_b, whh_b, b_b, ws);
  emis_k<<<dim3(128), dim3(256), 0, stream>>>(fc_w, fc_b, ws);
  cls_k<<<dim3(64), dim3(64), 0, stream>>>(fc2_w, fc2_b, ws, out);
  viterbi_k<<<dim3(64), dim3(64), 0, stream>>>(trans, ws, out);
}

// Round 11
// 2389.481 us; speedup vs baseline: 2.0982x; 1.0832x over previous
//
#include <hip/hip_runtime.h>
#include <stdint.h>
#include <math.h>

typedef __attribute__((ext_vector_type(8))) short bf16x8;
typedef __attribute__((ext_vector_type(4))) float f32x4;
typedef __attribute__((ext_vector_type(4))) unsigned short us4;
typedef __attribute__((ext_vector_type(4))) unsigned int ui4;

// ---------------- workspace layout (bytes) ----------------
constexpr size_t OFF_FLAGS  = 0;                          // 8 groups x 32 ints (pad to 4096)
constexpr size_t OFF_MASK   = 4096;                       // [512 t][64 b] f32 = 131072
constexpr size_t OFF_XE_H   = OFF_MASK + 131072;          // [512 t][64 b][256 k] bf16 = 16777216
constexpr size_t OFF_XE_L   = OFF_XE_H + 16777216;
constexpr size_t OFF_HSEQ   = OFF_XE_L + 16777216;        // [2 dir][64 b][512 t][512 k] f32 = 134217728
constexpr size_t OFF_HLAST  = OFF_HSEQ + 134217728;       // [2 dir][64 b][512 k] f32 = 262144
constexpr size_t OFF_EMIS   = OFF_HLAST + 262144;         // [64 b][512 t][12] f32 = 1572864
// total ~170 MB (proven footprint)

__device__ __forceinline__ unsigned short f2bf(float f) {
  unsigned u = __float_as_uint(f);
  unsigned r = 0x7fffu + ((u >> 16) & 1u);          // RNE
  return (unsigned short)((u + r) >> 16);
}
__device__ __forceinline__ float bf2f(unsigned short h) {
  return __uint_as_float(((unsigned)h) << 16);
}
__device__ __forceinline__ void split2(float v, unsigned short &a, unsigned short &b) {
  a = f2bf(v); b = f2bf(v - bf2f(a));
}
__device__ __forceinline__ void split3(float v, unsigned short &a, unsigned short &b, unsigned short &c) {
  a = f2bf(v); float r = v - bf2f(a);
  b = f2bf(r); float r2 = r - bf2f(b);
  c = f2bf(r2);
}
__device__ __forceinline__ float sigm(float x) {
  float e = expf(-fabsf(x));
  float s = 1.0f / (1.0f + e);
  return x >= 0.0f ? s : 1.0f - s;
}
__device__ __forceinline__ f32x4 mfma16(bf16x8 a, bf16x8 b, f32x4 c) {
  return __builtin_amdgcn_mfma_f32_16x16x32_bf16(a, b, c, 0, 0, 0);
}
// agent-scope (L3 write-through) store: the PROVEN h-handoff path (R8)
__device__ __forceinline__ void ast32(unsigned int* p, unsigned v) {
  __hip_atomic_store(p, v, __ATOMIC_RELAXED, __HIP_MEMORY_SCOPE_AGENT);
}

// ---------------- prep: embeddings gather + hi/lo split, mask, zero flags ----------------
__global__ __launch_bounds__(256) void prep_k(const int* __restrict__ x,
                                              const float* __restrict__ emb,
                                              char* __restrict__ ws)
{
  const int bid = blockIdx.x, tid = threadIdx.x;
  if (bid < 8192) {                       // xe: 32768 rows x 64 segs (4 floats each)
    const int gi = bid * 256 + tid;
    const int row = gi >> 6;              // b*512 + t
    const int k = (gi & 63) * 4;
    const int b = row >> 9, t = row & 511;
    const int xid = x[row];
    const float4 v = *(const float4*)(emb + (size_t)xid * 256 + k);
    float vv[4] = {v.x, v.y, v.z, v.w};
    us4 H, L;
    #pragma unroll
    for (int j = 0; j < 4; ++j) {
      unsigned short hj, lj;
      split2(vv[j], hj, lj);
      H[j] = hj; L[j] = lj;
    }
    const size_t o = ((size_t)t * 64 + b) * 256 + k;
    *(us4*)((unsigned short*)(ws + OFF_XE_H) + o) = H;
    *(us4*)((unsigned short*)(ws + OFF_XE_L) + o) = L;
  } else if (bid < 8320) {                // mask
    const int gi = (bid - 8192) * 256 + tid;   // b*512 + t
    const int b = gi >> 9, t = gi & 511;
    ((float*)(ws + OFF_MASK))[t * 64 + b] = (x[gi] != 0) ? 1.0f : 0.0f;
  } else {                                // zero barrier flags (whole 4096B header)
    for (int i = tid; i < 1024; i += 256) ((int*)ws)[i] = 0;
  }
}

// ---------------- persistent bidirectional LSTM (3-way-split bf16 MFMA, ~fp32-exact) ----------------
// 256 WGs x 256 threads. WG = (dir, mg: 16 batch rows, ng: 16 h-cols -> 64 gate cols).
// h handoff (R8-proven): producers agent-store fp32 h into hseq (never-reused addresses);
// consumers, gated by a 32-flag group barrier, read with plain cached float4 loads and
// split 3-way in registers (truncation split: exact decomposition, validated in R10 run 1).
__global__ __launch_bounds__(256, 1) void lstm_k(
    const float* __restrict__ wih_f, const float* __restrict__ whh_f, const float* __restrict__ b_f,
    const float* __restrict__ wih_b, const float* __restrict__ whh_b, const float* __restrict__ b_b,
    char* __restrict__ ws)
{
  int* flags = (int*)(ws + OFF_FLAGS);
  const float* maskf = (const float*)(ws + OFF_MASK);
  const unsigned short* xeH = (const unsigned short*)(ws + OFF_XE_H);
  const unsigned short* xeL = (const unsigned short*)(ws + OFF_XE_L);
  float* hseq  = (float*)(ws + OFF_HSEQ);
  float* hlast = (float*)(ws + OFF_HLAST);

  const int bid = blockIdx.x, tid = threadIdx.x;
  const int dir = bid & 1;
  const int mg  = (bid >> 1) & 3;          // batch group: rows [mg*16, mg*16+16)
  const int ng  = bid >> 3;                // 0..31: h-cols [ng*16, ng*16+16)
  int* gflags = flags + (dir * 4 + mg) * 32;   // group barrier: 32 flags

  const float* whh  = dir ? whh_b : whh_f;
  const float* wih  = dir ? wih_b : wih_f;
  const float* bias = dir ? b_b  : b_f;

  const int kh = tid >> 6, lane = tid & 63;
  const int quad = lane >> 4, n16 = lane & 15;
  const int bRow = mg * 16 + n16;          // A-operand row (batch index)

  // B-operand (W^T) fragments in registers: gate g = ni (0..3 = i,f,g,o)
  bf16x8 bhh[4][4][3];   // [kt][ni][plane] 3-way split
  bf16x8 bhx[2][4][2];   // [xi][ni][plane] 2-way split
  #pragma unroll
  for (int ni = 0; ni < 4; ++ni) {
    const int grow = ni * 512 + ng * 16 + n16;   // weight row (gate column)
    const float* hrow = whh + (size_t)grow * 512;
    const float* xrow = wih + (size_t)grow * 256;
    #pragma unroll
    for (int kt = 0; kt < 4; ++kt) {
      const int k = (4 * kt + kh) * 32 + quad * 8;
      union { bf16x8 v; unsigned short s[8]; } H, M, L;
      #pragma unroll
      for (int j = 0; j < 8; ++j) split3(hrow[k + j], H.s[j], M.s[j], L.s[j]);
      bhh[kt][ni][0] = H.v; bhh[kt][ni][1] = M.v; bhh[kt][ni][2] = L.v;
    }
    #pragma unroll
    for (int xi = 0; xi < 2; ++xi) {
      const int k = (2 * kh + xi) * 32 + quad * 8;
      union { bf16x8 v; unsigned short s[8]; } H, L;
      #pragma unroll
      for (int j = 0; j < 8; ++j) split2(xrow[k + j], H.s[j], L.s[j]);
      bhx[xi][ni][0] = H.v; bhx[xi][ni][1] = L.v;
    }
  }

  // cell-update mapping: 256 threads = 16 rows x 16 h-cols (hcU fastest -> coalesced)
  const int rowU = tid >> 4, hcU = tid & 15;
  const int bU = mg * 16 + rowU;
  const int hcol = ng * 16 + hcU;
  const float bI = bias[hcol];
  const float bF = bias[512 + hcol];
  const float bG = bias[1024 + hcol];
  const float bO = bias[1536 + hcol];
  float cstate = 0.0f, hcarry = 0.0f;

  __shared__ float gbuf[4][16][65];   // [kh][row][gatecol(+pad)]

  #pragma unroll 1
  for (int t = 0; t < 512; ++t) {
    const int tau = dir ? (511 - t) : t;
    f32x4 acc[4];
    const f32x4 z4 = {0.f, 0.f, 0.f, 0.f};
    #pragma unroll
    for (int ni = 0; ni < 4; ++ni) acc[ni] = z4;

    // ---- x-projection tiles: independent work, overlaps the flag wait below ----
    #pragma unroll
    for (int xi = 0; xi < 2; ++xi) {
      const int kx = (2 * kh + xi) * 32 + quad * 8;
      const size_t o = ((size_t)tau * 64 + bRow) * 256 + kx;
      bf16x8 aH = *(const bf16x8*)(xeH + o);
      bf16x8 aL = *(const bf16x8*)(xeL + o);
      #pragma unroll
      for (int ni = 0; ni < 4; ++ni) {
        f32x4 a = acc[ni];
        a = mfma16(aH, bhx[xi][ni][0], a);
        a = mfma16(aH, bhx[xi][ni][1], a);
        a = mfma16(aL, bhx[xi][ni][0], a);
        a = mfma16(aL, bhx[xi][ni][1], a);
        acc[ni] = a;
      }
    }

    // ---- group flag wait: peers finished storing h for step t-1 ----
    if (t > 0) {
      if (tid < 32) {
        while (__hip_atomic_load(&gflags[tid], __ATOMIC_RELAXED, __HIP_MEMORY_SCOPE_AGENT) < t)
          __builtin_amdgcn_s_sleep(1);
      }
    }
    __syncthreads();   // sync#1: gates first touch of hseq[tauP]

    // ---- recurrent tiles: cached float4 loads, truncation 3-way split, MFMA ----
    if (t > 0) {
      const int tauP = dir ? (tau + 1) : (tau - 1);
      const float* hb = hseq + (((size_t)dir * 64 + bRow) * 512 + tauP) * 512;
      float4 hv[8];
      #pragma unroll
      for (int kt = 0; kt < 4; ++kt) {
        const int k = (4 * kt + kh) * 32 + quad * 8;
        hv[2 * kt]     = *(const float4*)(hb + k);
        hv[2 * kt + 1] = *(const float4*)(hb + k + 4);
      }
      #pragma unroll
      for (int kt = 0; kt < 4; ++kt) {
        union { bf16x8 v; unsigned short s[8]; } H, M, L;
        float vv[8];
        *(float4*)&vv[0] = hv[2 * kt];
        *(float4*)&vv[4] = hv[2 * kt + 1];
        #pragma unroll
        for (int j = 0; j < 8; ++j) {
          // truncation split: v = hi + mi + r2 exactly; L = trunc(r2) (err ~2^-24|v|)
          const unsigned u0 = __float_as_uint(vv[j]);
          const float hi = __uint_as_float(u0 & 0xffff0000u);
          const float r1 = vv[j] - hi;
          const unsigned u1 = __float_as_uint(r1);
          const float mi = __uint_as_float(u1 & 0xffff0000u);
          const float r2 = r1 - mi;
          const unsigned u2 = __float_as_uint(r2);
          H.s[j] = (unsigned short)(u0 >> 16);
          M.s[j] = (unsigned short)(u1 >> 16);
          L.s[j] = (unsigned short)(u2 >> 16);
        }
        #pragma unroll
        for (int ni = 0; ni < 4; ++ni) {
          f32x4 a = acc[ni];
          a = mfma16(H.v, bhh[kt][ni][0], a);
          a = mfma16(H.v, bhh[kt][ni][1], a);
          a = mfma16(M.v, bhh[kt][ni][0], a);
          a = mfma16(H.v, bhh[kt][ni][2], a);
          a = mfma16(M.v, bhh[kt][ni][1], a);
          a = mfma16(L.v, bhh[kt][ni][0], a);
          acc[ni] = a;
        }
      }
    }

    // ---- gates -> LDS (C/D layout: col = lane&15, row = quad*4 + reg) ----
    #pragma unroll
    for (int ni = 0; ni < 4; ++ni)
      #pragma unroll
      for (int r = 0; r < 4; ++r)
        gbuf[kh][quad * 4 + r][ni * 16 + n16] = acc[ni][r];
    __syncthreads();   // sync#2

    // ---- LSTM cell update ----
    const float gi = gbuf[0][rowU][hcU]      + gbuf[1][rowU][hcU]      + gbuf[2][rowU][hcU]      + gbuf[3][rowU][hcU]      + bI;
    const float gf = gbuf[0][rowU][16 + hcU] + gbuf[1][rowU][16 + hcU] + gbuf[2][rowU][16 + hcU] + gbuf[3][rowU][16 + hcU] + bF;
    const float gg = gbuf[0][rowU][32 + hcU] + gbuf[1][rowU][32 + hcU] + gbuf[2][rowU][32 + hcU] + gbuf[3][rowU][32 + hcU] + bG;
    const float go = gbuf[0][rowU][48 + hcU] + gbuf[1][rowU][48 + hcU] + gbuf[2][rowU][48 + hcU] + gbuf[3][rowU][48 + hcU] + bO;
    const float m = maskf[tau * 64 + bU];
    const float iv = sigm(gi), fv = sigm(gf), gv = tanhf(gg), ov = sigm(go);
    const float cn = fv * cstate + iv * gv;
    const float hn = ov * tanhf(cn);
    const bool mm = (m > 0.5f);
    cstate = mm ? cn : cstate;
    hcarry = mm ? hn : hcarry;

    // h for recurrence + emissions: agent store (write-through, L3-visible) -- proven path.
    ast32((unsigned int*)(hseq + (((size_t)dir * 64 + bU) * 512 + tau) * 512 + hcol),
          __float_as_uint(mm ? hn : 0.0f));

    __syncthreads();   // sync#3: drains vmcnt -> this WG's h stores are in L3
    if (tid == 0)
      __hip_atomic_store(&gflags[ng], t + 1, __ATOMIC_RELAXED, __HIP_MEMORY_SCOPE_AGENT);
  }

  hlast[((size_t)dir * 64 + bU) * 512 + hcol] = hcarry;
}

// ---------------- emissions: hiddens @ fc_w^T + fc_b (fp64 accumulate) ----------------
__global__ __launch_bounds__(256) void emis_k(const float* __restrict__ fc_w,
                                              const float* __restrict__ fc_b,
                                              char* __restrict__ ws)
{
  __shared__ __align__(16) float fw[12 * 1024];
  __shared__ float fb[12];
  const int tid = threadIdx.x;
  for (int i = tid; i < 12 * 1024; i += 256) fw[i] = fc_w[i];
  if (tid < 12) fb[tid] = fc_b[tid];
  __syncthreads();
  const int row = blockIdx.x * 256 + tid;   // b*512 + tau
  const int b = row >> 9, tau = row & 511;
  const float* hs = (const float*)(ws + OFF_HSEQ);
  double acc[12];
  #pragma unroll
  for (int n = 0; n < 12; ++n) acc[n] = (double)fb[n];
  #pragma unroll 1
  for (int d = 0; d < 2; ++d) {
    const float4* hp = (const float4*)(hs + (((size_t)d * 64 + b) * 512 + tau) * 512);
    const float* fwd = fw + d * 512;
    for (int k4 = 0; k4 < 128; ++k4) {
      const float4 hv = hp[k4];
      #pragma unroll
      for (int n = 0; n < 12; ++n) {
        const float4 wv = *(const float4*)(fwd + n * 1024 + k4 * 4);
        acc[n] += (double)hv.x * wv.x + (double)hv.y * wv.y
                + (double)hv.z * wv.z + (double)hv.w * wv.w;
      }
    }
  }
  float* em = (float*)(ws + OFF_EMIS);
  #pragma unroll
  for (int n = 0; n < 12; ++n) em[(size_t)row * 12 + n] = (float)acc[n];
}

// ---------------- Viterbi decode (one wave per batch element) ----------------
__global__ __launch_bounds__(64) void viterbi_k(const float* __restrict__ trans,
                                                char* __restrict__ ws,
                                                float* __restrict__ out)
{
  const int b = blockIdx.x, lane = threadIdx.x;
  const float* eb = (const float*)(ws + OFF_EMIS) + (size_t)b * 6144;
  const float* maskf = (const float*)(ws + OFF_MASK);
  __shared__ float se[6144];
  __shared__ float sm[512];
  __shared__ unsigned char bp[512][12];
  for (int i = lane; i < 6144; i += 64) se[i] = eb[i];
  for (int i = lane; i < 512; i += 64) sm[i] = maskf[i * 64 + b];
  __syncthreads();
  const bool act = lane < 12;
  float tr[12];                         // tr[i] = trans[i][lane]
  #pragma unroll
  for (int i = 0; i < 12; ++i) tr[i] = act ? trans[i * 12 + lane] : 0.0f;
  float alpha = act ? (trans[120 + lane] + se[lane]) : -3.0e38f;   // BOS=10
  for (int t = 1; t < 512; ++t) {
    const float m = sm[t];
    float best = -3.0e38f; int bpi = 0;
    #pragma unroll
    for (int i = 0; i < 12; ++i) {
      const float s = __shfl(alpha, i) + tr[i];
      if (s > best) { best = s; bpi = i; }   // strict > keeps first max (jnp.argmax)
    }
    const float ev = act ? se[t * 12 + lane] : 0.0f;
    if (m > 0.5f) alpha = best + ev; else bpi = lane;
    if (act) bp[t][lane] = (unsigned char)bpi;
  }
  const float fin = act ? (alpha + trans[lane * 12 + 11]) : -3.0e38f;  // EOS=11
  float bestf = -3.0e38f; int bt = 0;
  #pragma unroll
  for (int j = 0; j < 12; ++j) {
    const float v = __shfl(fin, j);
    if (v > bestf) { bestf = v; bt = j; }
  }
  __syncthreads();
  if (lane == 0) {
    out[b] = bestf;
    int tag = bt;
    for (int t = 511; t >= 1; --t) {
      out[64 + (size_t)b * 512 + t] = (sm[t] > 0.5f) ? (float)tag : 0.0f;  // PAD=0
      tag = bp[t][tag];
    }
    out[64 + (size_t)b * 512] = (float)tag;   // t=0 always valid (len >= 256)
  }
}

// ---------------- classifier head: softmax(last_hidden @ fc2_w^T + fc2_b) ----------------
__global__ __launch_bounds__(64) void cls_k(const float* __restrict__ fc2_w,
                                            const float* __restrict__ fc2_b,
                                            char* __restrict__ ws,
                                            float* __restrict__ out)
{
  const int b = blockIdx.x, lane = threadIdx.x;
  const float* hl = (const float*)(ws + OFF_HLAST);
  float acc[10];
  #pragma unroll
  for (int c = 0; c < 10; ++c) acc[c] = 0.0f;
  #pragma unroll 1
  for (int kk = 0; kk < 16; ++kk) {
    const int k = lane * 16 + kk;
    const float hv = (k < 512) ? hl[(size_t)b * 512 + k]
                               : hl[((size_t)(64 + b)) * 512 + (k - 512)];
    #pragma unroll
    for (int c = 0; c < 10; ++c) acc[c] += hv * fc2_w[c * 1024 + k];
  }
  #pragma unroll
  for (int c = 0; c < 10; ++c) {
    #pragma unroll
    for (int off = 32; off >= 1; off >>= 1)
      acc[c] += __shfl_down(acc[c], off);
  }
  if (lane == 0) {
    float lg[10];
    float mx = -3.0e38f;
    #pragma unroll
    for (int c = 0; c < 10; ++c) { lg[c] = acc[c] + fc2_b[c]; mx = fmaxf(mx, lg[c]); }
    float s = 0.0f;
    #pragma unroll
    for (int c = 0; c < 10; ++c) { lg[c] = expf(lg[c] - mx); s += lg[c]; }
    const float inv = 1.0f / s;
    #pragma unroll
    for (int c = 0; c < 10; ++c) out[32832 + b * 10 + c] = lg[c] * inv;
  }
}

extern "C" void kernel_launch(void* const* d_in, const int* in_sizes, int n_in,
                              void* d_out, int out_size, void* d_ws, size_t ws_size,
                              hipStream_t stream)
{
  (void)in_sizes; (void)n_in; (void)out_size; (void)ws_size;
  const int*   x      = (const int*)d_in[0];
  const float* emb    = (const float*)d_in[1];
  const float* wih_f  = (const float*)d_in[2];
  const float* whh_f  = (const float*)d_in[3];
  const float* b_f    = (const float*)d_in[4];
  const float* wih_b  = (const float*)d_in[5];
  const float* whh_b  = (const float*)d_in[6];
  const float* b_b    = (const float*)d_in[7];
  const float* fc_w   = (const float*)d_in[8];
  const float* fc_b   = (const float*)d_in[9];
  const float* fc2_w  = (const float*)d_in[10];
  const float* fc2_b  = (const float*)d_in[11];
  const float* trans  = (const float*)d_in[12];
  char* ws = (char*)d_ws;
  float* out = (float*)d_out;

  prep_k<<<dim3(8321), dim3(256), 0, stream>>>(x, emb, ws);
  lstm_k<<<dim3(256), dim3(256), 0, stream>>>(wih_f, whh_f, b_f, wih_b, whh_b, b_b, ws);
  emis_k<<<dim3(128), dim3(256), 0, stream>>>(fc_w, fc_b, ws);
  cls_k<<<dim3(64), dim3(64), 0, stream>>>(fc2_w, fc2_b, ws, out);
  viterbi_k<<<dim3(64), dim3(64), 0, stream>>>(trans, ws, out);
}